// Round 12
// baseline (1324.923 us; speedup 1.0000x reference)
//
#include <hip/hip_runtime.h>
#include <hip/hip_bf16.h>
#include <cstdint>

using bf16 = __hip_bfloat16;
typedef __bf16 bf16x8 __attribute__((ext_vector_type(8)));
typedef float f32x4 __attribute__((ext_vector_type(4)));

constexpr int Hd = 512;
constexpr int Ld = 6;
constexpr int Fd = 2048;
constexpr int Vd = 50304;
constexpr int Vpad = 50432;  // 197*256
constexpr int Md = 4096;     // B*S

// ---------- helpers ----------
__device__ __forceinline__ unsigned short f2b(float x) {
  return __builtin_bit_cast(unsigned short, __float2bfloat16(x));
}

__device__ __forceinline__ float gelu_tanh(float x) {
  const float c = 0.7978845608028654f;  // sqrt(2/pi)
  float x3 = x * x * x;
  return 0.5f * x * (1.0f + tanhf(c * (x + 0.044715f * x3)));
}

__device__ __forceinline__ void load16_lds(const bf16* g, bf16* l) {
  __builtin_amdgcn_global_load_lds(
      (const __attribute__((address_space(1))) void*)g,
      (__attribute__((address_space(3))) void*)l, 16, 0, 0);
}

// ---------- combined weight cast: hp (n8hp) then eow+pad (n8cast/n8tot) ----------
__global__ __launch_bounds__(256) void cast_weights(
    const float* __restrict__ hp, bf16* __restrict__ hpB, int n8hp,
    const float* __restrict__ eow, bf16* __restrict__ eowB, int n8cast, int n8tot) {
  int i = blockIdx.x * 256 + threadIdx.x;
  if (i < n8hp) {
    const float4* p = (const float4*)hp;
    float4 a = p[2 * i], b = p[2 * i + 1];
    uint4 o = {(unsigned)f2b(a.x) | ((unsigned)f2b(a.y) << 16),
               (unsigned)f2b(a.z) | ((unsigned)f2b(a.w) << 16),
               (unsigned)f2b(b.x) | ((unsigned)f2b(b.y) << 16),
               (unsigned)f2b(b.z) | ((unsigned)f2b(b.w) << 16)};
    ((uint4*)hpB)[i] = o;
    return;
  }
  int j = i - n8hp;
  if (j >= n8tot) return;
  if (j < n8cast) {
    const float4* p = (const float4*)eow;
    float4 a = p[2 * j], b = p[2 * j + 1];
    uint4 o = {(unsigned)f2b(a.x) | ((unsigned)f2b(a.y) << 16),
               (unsigned)f2b(a.z) | ((unsigned)f2b(a.w) << 16),
               (unsigned)f2b(b.x) | ((unsigned)f2b(b.y) << 16),
               (unsigned)f2b(b.z) | ((unsigned)f2b(b.w) << 16)};
    ((uint4*)eowB)[j] = o;
  } else {
    ((uint4*)eowB)[j] = uint4{0, 0, 0, 0};
  }
}

// ---------- combined transpose+cast for W1 (z<6) and W2 (z>=6) ----------
__global__ void transpose_cast2(const float* __restrict__ W1, bf16* __restrict__ W1t,
                                const float* __restrict__ W2, bf16* __restrict__ W2t) {
  __shared__ float tile[32][33];
  const int z = blockIdx.z;
  const bool isW1 = z < Ld;
  const int layer = isW1 ? z : z - Ld;
  const int R = isW1 ? Hd : Fd;
  const int C = isW1 ? Fd : Hd;
  const float* in = (isW1 ? W1 : W2) + (size_t)layer * R * C;
  bf16* out = (isW1 ? W1t : W2t) + (size_t)layer * R * C;
  const int tilesX = C >> 5;
  const int bx = blockIdx.x % tilesX;
  const int by = blockIdx.x / tilesX;
  int c0 = bx * 32, r0 = by * 32;
#pragma unroll
  for (int i = 0; i < 4; i++) {
    int r = r0 + threadIdx.y + i * 8;
    tile[threadIdx.y + i * 8][threadIdx.x] = in[(size_t)r * C + c0 + threadIdx.x];
  }
  __syncthreads();
#pragma unroll
  for (int i = 0; i < 4; i++) {
    int c = c0 + threadIdx.y + i * 8;
    out[(size_t)c * R + r0 + threadIdx.x] = (bf16)tile[threadIdx.x][threadIdx.y + i * 8];
  }
}

// ---------- fused embedding gather + LN_0 ----------
__global__ __launch_bounds__(256) void ln_gather(
    const int* __restrict__ ids, const float* __restrict__ emb,
    const float* __restrict__ w, const float* __restrict__ b,
    float* __restrict__ hout, bf16* __restrict__ y) {
  int row = blockIdx.x * 4 + (threadIdx.x >> 6);
  int lane = threadIdx.x & 63;
  size_t base = (size_t)row * Hd + lane * 8;
  int id = ids[row];
  const float* src = emb + (size_t)id * Hd + lane * 8;
  float xv[8];
  *(float4*)&xv[0] = *(const float4*)(src);
  *(float4*)&xv[4] = *(const float4*)(src + 4);
  *(float4*)(hout + base) = make_float4(xv[0], xv[1], xv[2], xv[3]);
  *(float4*)(hout + base + 4) = make_float4(xv[4], xv[5], xv[6], xv[7]);
  float s = 0.f;
#pragma unroll
  for (int j = 0; j < 8; j++) s += xv[j];
#pragma unroll
  for (int off = 1; off < 64; off <<= 1) s += __shfl_xor(s, off);
  float mu = s * (1.0f / 512.0f);
  float s2 = 0.f;
#pragma unroll
  for (int j = 0; j < 8; j++) {
    xv[j] -= mu;
    s2 += xv[j] * xv[j];
  }
#pragma unroll
  for (int off = 1; off < 64; off <<= 1) s2 += __shfl_xor(s2, off);
  float scale = rsqrtf(s2 * (1.0f / 512.0f) + 1e-5f);
  float o[8];
#pragma unroll
  for (int j = 0; j < 8; j++) o[j] = xv[j] * scale * w[lane * 8 + j] + b[lane * 8 + j];
  uint4 pk = {(unsigned)f2b(o[0]) | ((unsigned)f2b(o[1]) << 16),
              (unsigned)f2b(o[2]) | ((unsigned)f2b(o[3]) << 16),
              (unsigned)f2b(o[4]) | ((unsigned)f2b(o[5]) << 16),
              (unsigned)f2b(o[6]) | ((unsigned)f2b(o[7]) << 16)};
  *(uint4*)(y + base) = pk;
}

// ---------- GEMM 256x128 tile, BK=64, 512 thr, 3-slot counted-vmcnt (gemm1) ----------
template <int EPI>
__global__ __launch_bounds__(512) void gemm_bt256(
    const bf16* __restrict__ A, const bf16* __restrict__ Bt,
    const float* __restrict__ bias, float* __restrict__ outF,
    bf16* __restrict__ outB, int M, int N, int lda, int ldb) {
  constexpr int ASZ = 256 * 64;          // 32 KB
  constexpr int BSZ = 128 * 64;          // 16 KB
  constexpr int TILE = ASZ + BSZ;        // 48 KB
  __shared__ bf16 lds[3 * TILE];         // 144 KB
  const int tid = threadIdx.x;
  const int wave = tid >> 6;
  const int lane = tid & 63;
  const int wm = (wave >> 1) * 64;
  const int wn = (wave & 1) * 64;

  const int bn = blockIdx.x;
  const int bm = blockIdx.y;
  const int rowA0 = bm * 256;
  const int rowB0 = bn * 128;

  const bf16* srcA[4];
#pragma unroll
  for (int r = 0; r < 4; r++) {
    int c = r * 512 + tid;
    int row = c >> 3, d = c & 7;
    int cw = d ^ (row & 7);
    srcA[r] = A + (size_t)(rowA0 + row) * lda + cw * 8;
  }
  const bf16* srcB[2];
#pragma unroll
  for (int r = 0; r < 2; r++) {
    int c = r * 512 + tid;
    int row = c >> 3, d = c & 7;
    int cw = d ^ (row & 7);
    srcB[r] = Bt + (size_t)(rowB0 + row) * ldb + cw * 8;
  }

  f32x4 acc[4][4];
#pragma unroll
  for (int i = 0; i < 4; i++)
#pragma unroll
    for (int j = 0; j < 4; j++) acc[i][j] = (f32x4){0.f, 0.f, 0.f, 0.f};

  const int fr = lane & 15;
  const int hi = lane >> 4;
  const int swz = fr & 7;

  auto STAGE = [&](int slot) {
    bf16* dst = lds + slot * TILE;
#pragma unroll
    for (int r = 0; r < 4; r++) {
      load16_lds(srcA[r], dst + (r * 8 + wave) * 512);
      srcA[r] += 64;
    }
#pragma unroll
    for (int r = 0; r < 2; r++) {
      load16_lds(srcB[r], dst + ASZ + (r * 8 + wave) * 512);
      srcB[r] += 64;
    }
  };

  STAGE(0);
  STAGE(1);
  const int nIter = 512 >> 6;  // K = Hd
  int cur = 0, stg = 2;
  for (int it = 0; it < nIter; ++it) {
    if (it < nIter - 1)
      asm volatile("s_waitcnt vmcnt(6)" ::: "memory");
    else
      asm volatile("s_waitcnt vmcnt(0)" ::: "memory");
    __builtin_amdgcn_s_barrier();
    __builtin_amdgcn_sched_barrier(0);
    if (it + 2 < nIter) STAGE(stg);
    const bf16* lA = lds + cur * TILE;
    const bf16* lB = lA + ASZ;
#pragma unroll
    for (int ks = 0; ks < 2; ks++) {
      bf16x8 af[4], bfr[4];
#pragma unroll
      for (int f = 0; f < 4; f++) {
        int rowa = wm + f * 16 + fr;
        af[f] = *(const bf16x8*)(lA + rowa * 64 + ((ks * 4 + hi) ^ swz) * 8);
        int rowb = wn + f * 16 + fr;
        bfr[f] = *(const bf16x8*)(lB + rowb * 64 + ((ks * 4 + hi) ^ swz) * 8);
      }
#pragma unroll
      for (int i = 0; i < 4; i++)
#pragma unroll
        for (int j = 0; j < 4; j++)
          acc[i][j] = __builtin_amdgcn_mfma_f32_16x16x32_bf16(af[i], bfr[j], acc[i][j], 0, 0, 0);
    }
    cur = (cur == 2) ? 0 : cur + 1;
    stg = (stg == 2) ? 0 : stg + 1;
  }

  const int orow = hi * 4;
  const int ocol = fr;
#pragma unroll
  for (int i = 0; i < 4; i++) {
#pragma unroll
    for (int j = 0; j < 4; j++) {
      int row0 = rowA0 + wm + i * 16 + orow;
      int col = rowB0 + wn + j * 16 + ocol;
#pragma unroll
      for (int q = 0; q < 4; q++) {
        float v = acc[i][j][q];
        size_t idx = (size_t)(row0 + q) * N + col;
        if constexpr (EPI == 0) {
          outB[idx] = (bf16)gelu_tanh(v + bias[col]);
        } else {
          outF[idx] = v;
        }
      }
    }
  }
}

// ---------- fused gemm2 + bias + residual + LayerNorm + bf16 emit ----------
// Tile 64 (M) x 512 (full N), BK=64, 256 thr (4 waves, wave = 64x128).
// 2-slot 2-barrier counted-vmcnt(18) pipeline. Grid = Md/64 = 64 blocks.
// MODE 0: v = acc+fb+h; h=v; y = LN(v; lw,lb)          (stack layers 0-4)
// MODE 1: v = acc+fb+h; h=v; y = bf16(v)               (stack1 L5 -> hp input)
// MODE 2: v = acc+fb;   h=v; y = LN(v; lw,lb)          (hp projection)
// MODE 3: v = acc+fb+h; y = LN(v; lnf); tail rows->out2; no h store (final)
template <int MODE>
__global__ __launch_bounds__(256) void gemm2_ln(
    const bf16* __restrict__ A, const bf16* __restrict__ Bt,
    const float* __restrict__ fb, const float* __restrict__ lw,
    const float* __restrict__ lb, float* __restrict__ h,
    bf16* __restrict__ y, float* __restrict__ out2, int K) {
  constexpr int ASZ = 64 * 64;     // 4096 elems (8 KB)
  constexpr int BSZ = 512 * 64;    // 32768 elems (64 KB)
  constexpr int TILE = ASZ + BSZ;  // 72 KB
  __shared__ bf16 lds[2 * TILE];   // 144 KB
  const int tid = threadIdx.x;
  const int wave = tid >> 6;
  const int lane = tid & 63;
  const int fr = lane & 15;
  const int hi = lane >> 4;
  const int swz = fr & 7;
  const int rowA0 = blockIdx.x * 64;
  const int wn = wave * 128;

  // staging bases: chunk c = r*256+tid -> row = r*32 + (tid>>3), d = tid&7.
  // row&7 == (tid>>3)&7 (r*32 % 8 == 0) -> swizzled col cw is r-invariant.
  const int rsel = tid >> 3;
  const int cw = (tid & 7) ^ (rsel & 7);
  const bf16* srcA0 = A + (size_t)(rowA0 + rsel) * K + cw * 8;
  const bf16* srcB0 = Bt + (size_t)rsel * K + cw * 8;
  int koff = 0;

  f32x4 acc[4][8];
#pragma unroll
  for (int i = 0; i < 4; i++)
#pragma unroll
    for (int j = 0; j < 8; j++) acc[i][j] = (f32x4){0.f, 0.f, 0.f, 0.f};

  auto STAGE = [&]() {
    int slot = (koff >> 6) & 1;
    bf16* dst = lds + slot * TILE;
#pragma unroll
    for (int r = 0; r < 2; r++)
      load16_lds(srcA0 + (size_t)(r * 32) * K + koff, dst + (r * 256 + tid) * 8);
#pragma unroll
    for (int r = 0; r < 16; r++)
      load16_lds(srcB0 + (size_t)(r * 32) * K + koff, dst + ASZ + (r * 256 + tid) * 8);
    koff += 64;
  };

  STAGE();  // slot 0
  const int nIter = K >> 6;
  for (int it = 0; it < nIter; ++it) {
    const int cur = it & 1;
    if (it + 1 < nIter) {
      STAGE();  // into slot cur^1
      asm volatile("s_waitcnt vmcnt(18)" ::: "memory");  // cur's 18 complete
    } else {
      asm volatile("s_waitcnt vmcnt(0)" ::: "memory");
    }
    __builtin_amdgcn_s_barrier();
    __builtin_amdgcn_sched_barrier(0);
    const bf16* lA = lds + cur * TILE;
    const bf16* lB = lA + ASZ;
#pragma unroll
    for (int ks = 0; ks < 2; ks++) {
      bf16x8 af[4], bfr[8];
#pragma unroll
      for (int i = 0; i < 4; i++) {
        int rowa = i * 16 + fr;
        af[i] = *(const bf16x8*)(lA + rowa * 64 + ((ks * 4 + hi) ^ swz) * 8);
      }
#pragma unroll
      for (int j = 0; j < 8; j++) {
        int rowb = wn + j * 16 + fr;
        bfr[j] = *(const bf16x8*)(lB + rowb * 64 + ((ks * 4 + hi) ^ swz) * 8);
      }
#pragma unroll
      for (int i = 0; i < 4; i++)
#pragma unroll
        for (int j = 0; j < 8; j++)
          acc[i][j] = __builtin_amdgcn_mfma_f32_16x16x32_bf16(af[i], bfr[j], acc[i][j], 0, 0, 0);
    }
    __builtin_amdgcn_s_barrier();  // all waves done reading cur before overwrite
  }

  // ---- epilogue: v = acc + fb (+ h residual), then row LN across 512 cols ----
  float fbv[8], lwv[8], lbv[8];
#pragma unroll
  for (int j = 0; j < 8; j++) {
    int col = wn + j * 16 + fr;
    fbv[j] = fb[col];
    if constexpr (MODE != 1) {
      lwv[j] = lw[col];
      lbv[j] = lb[col];
    }
  }

  float sum[4][4], sq[4][4];
#pragma unroll
  for (int i = 0; i < 4; i++) {
#pragma unroll
    for (int q = 0; q < 4; q++) {
      sum[i][q] = 0.f;
      sq[i][q] = 0.f;
      int row = rowA0 + i * 16 + hi * 4 + q;
#pragma unroll
      for (int j = 0; j < 8; j++) {
        float v = acc[i][j][q] + fbv[j];
        if constexpr (MODE != 2) v += h[(size_t)row * Hd + wn + j * 16 + fr];
        acc[i][j][q] = v;
        sum[i][q] += v;
        sq[i][q] += v * v;
      }
    }
  }

  if constexpr (MODE != 1) {
    // intra-wave reduce over fr (16 lanes hold the wave's 128-col slice of each row)
#pragma unroll
    for (int i = 0; i < 4; i++)
#pragma unroll
      for (int q = 0; q < 4; q++) {
        float s = sum[i][q], s2 = sq[i][q];
#pragma unroll
        for (int off = 1; off < 16; off <<= 1) {
          s += __shfl_xor(s, off);
          s2 += __shfl_xor(s2, off);
        }
        sum[i][q] = s;
        sq[i][q] = s2;
      }
    // cross-wave via LDS (safe: end-barrier of last iter passed)
    float* red = (float*)lds;  // [wave][64 rows][2]
    if (fr == 0) {
#pragma unroll
      for (int i = 0; i < 4; i++)
#pragma unroll
        for (int q = 0; q < 4; q++) {
          int rl = i * 16 + hi * 4 + q;
          red[(wave * 64 + rl) * 2 + 0] = sum[i][q];
          red[(wave * 64 + rl) * 2 + 1] = sq[i][q];
        }
    }
    __syncthreads();
#pragma unroll
    for (int i = 0; i < 4; i++)
#pragma unroll
      for (int q = 0; q < 4; q++) {
        int rl = i * 16 + hi * 4 + q;
        float S = 0.f, S2 = 0.f;
#pragma unroll
        for (int w = 0; w < 4; w++) {
          S += red[(w * 64 + rl) * 2 + 0];
          S2 += red[(w * 64 + rl) * 2 + 1];
        }
        float mu = S * (1.0f / 512.0f);
        float var = S2 * (1.0f / 512.0f) - mu * mu;
        sum[i][q] = mu;                       // reuse: mu
        sq[i][q] = rsqrtf(var + 1e-5f);       // reuse: rsig
      }
  }

  // ---- writes ----
#pragma unroll
  for (int i = 0; i < 4; i++) {
#pragma unroll
    for (int q = 0; q < 4; q++) {
      int row = rowA0 + i * 16 + hi * 4 + q;
      bool tail = (MODE == 3) && ((row & 1023) == 1023);
#pragma unroll
      for (int j = 0; j < 8; j++) {
        int col = wn + j * 16 + fr;
        float v = acc[i][j][q];
        if constexpr (MODE != 3) h[(size_t)row * Hd + col] = v;
        float o;
        if constexpr (MODE == 1) o = v;
        else o = (v - sum[i][q]) * sq[i][q] * lwv[j] + lbv[j];
        y[(size_t)row * Hd + col] = (bf16)o;
        if (tail) out2[(size_t)(row >> 10) * Hd + col] = v;
      }
    }
  }
}

// ---------- logits GEMM: 256x256 tile, BK=64, 512 thr, 2-slot 2-barrier ----------
__global__ __launch_bounds__(512, 1) void gemm_logits(
    const bf16* __restrict__ A, const bf16* __restrict__ Bt,
    float* __restrict__ outF, int M, int N, int lda, int ldb) {
  constexpr int ASZ = 256 * 64;     // 32 KB
  constexpr int TILE = 2 * ASZ;     // 64 KB
  __shared__ bf16 lds[2 * TILE];    // 128 KB
  const int tid = threadIdx.x;
  const int wave = tid >> 6;
  const int lane = tid & 63;
  const int wm = (wave >> 2) * 128;  // 0,128
  const int wn = (wave & 3) * 64;    // 0,64,128,192

  const int per = gridDim.x >> 3;
  const int wg = (blockIdx.x & 7) * per + (blockIdx.x >> 3);
  const int bm = wg & 15;
  const int bn = wg >> 4;
  const int rowA0 = bm * 256;
  const int rowB0 = bn * 256;

  const bf16* srcA[4];
  const bf16* srcB[4];
#pragma unroll
  for (int r = 0; r < 4; r++) {
    int c = r * 512 + tid;
    int row = c >> 3, d = c & 7;
    int cw = d ^ (row & 7);
    srcA[r] = A + (size_t)(rowA0 + row) * lda + cw * 8;
    srcB[r] = Bt + (size_t)(rowB0 + row) * ldb + cw * 8;
  }

  f32x4 acc[8][4];
#pragma unroll
  for (int i = 0; i < 8; i++)
#pragma unroll
    for (int j = 0; j < 4; j++) acc[i][j] = (f32x4){0.f, 0.f, 0.f, 0.f};

  const int fr = lane & 15;
  const int hi = lane >> 4;
  const int swz = fr & 7;

  auto STAGE = [&](int slot) {
    bf16* dst = lds + slot * TILE;
#pragma unroll
    for (int r = 0; r < 4; r++) {
      load16_lds(srcA[r], dst + (r * 8 + wave) * 512);
      srcA[r] += 64;
      load16_lds(srcB[r], dst + ASZ + (r * 8 + wave) * 512);
      srcB[r] += 64;
    }
  };

  STAGE(0);
  const int nIter = 512 >> 6;  // 8 iters
  for (int it = 0; it < nIter; ++it) {
    const int cur = it & 1;
    if (it + 1 < nIter) STAGE(cur ^ 1);
    if (it + 1 < nIter)
      asm volatile("s_waitcnt vmcnt(8)" ::: "memory");
    else
      asm volatile("s_waitcnt vmcnt(0)" ::: "memory");
    __builtin_amdgcn_s_barrier();
    __builtin_amdgcn_sched_barrier(0);
    const bf16* lA = lds + cur * TILE;
    const bf16* lB = lA + ASZ;
#pragma unroll
    for (int ks = 0; ks < 2; ks++) {
      bf16x8 af[8], bfr[4];
#pragma unroll
      for (int f = 0; f < 8; f++) {
        int rowa = wm + f * 16 + fr;
        af[f] = *(const bf16x8*)(lA + rowa * 64 + ((ks * 4 + hi) ^ swz) * 8);
      }
#pragma unroll
      for (int f = 0; f < 4; f++) {
        int rowb = wn + f * 16 + fr;
        bfr[f] = *(const bf16x8*)(lB + rowb * 64 + ((ks * 4 + hi) ^ swz) * 8);
      }
#pragma unroll
      for (int i = 0; i < 8; i++)
#pragma unroll
        for (int j = 0; j < 4; j++)
          acc[i][j] = __builtin_amdgcn_mfma_f32_16x16x32_bf16(af[i], bfr[j], acc[i][j], 0, 0, 0);
    }
    __builtin_amdgcn_s_barrier();
  }

  const int orow = hi * 4;
  const int ocol = fr;
#pragma unroll
  for (int i = 0; i < 8; i++) {
#pragma unroll
    for (int j = 0; j < 4; j++) {
      int row0 = rowA0 + wm + i * 16 + orow;
      int col = rowB0 + wn + j * 16 + ocol;
      if (col < N) {
#pragma unroll
        for (int q = 0; q < 4; q++)
          outF[(size_t)(row0 + q) * N + col] = acc[i][j][q];
      }
    }
  }
}

// ---------- launch ----------
extern "C" void kernel_launch(void* const* d_in, const int* in_sizes, int n_in,
                              void* d_out, int out_size, void* d_ws, size_t ws_size,
                              hipStream_t stream) {
  const int* ids = (const int*)d_in[0];
  const float* emb = (const float*)d_in[1];
  const float* hp_w = (const float*)d_in[2];
  const float* hp_b = (const float*)d_in[3];
  const float* ln_w = (const float*)d_in[4];
  const float* ln_b = (const float*)d_in[5];
  const float* W1 = (const float*)d_in[6];
  const float* b1 = (const float*)d_in[7];
  const float* W2 = (const float*)d_in[8];
  const float* b2 = (const float*)d_in[9];
  const float* lnf_w = (const float*)d_in[10];
  const float* lnf_b = (const float*)d_in[11];
  const float* eow = (const float*)d_in[12];
  float* out = (float*)d_out;

  char* ws = (char*)d_ws;
  float* h = (float*)(ws);                          // 8 MB
  bf16* ybf = (bf16*)(ws + (8u << 20));             // 4 MB
  bf16* abf = (bf16*)(ws + (12u << 20));            // 16 MB
  bf16* W1t = (bf16*)(ws + (28u << 20));            // 12 MB
  bf16* W2t = (bf16*)(ws + (40u << 20));            // 12 MB
  bf16* hpwB = (bf16*)(ws + (52u << 20));           // 0.5 MB
  bf16* eowB = (bf16*)(ws + (53u << 20));           // 51.6 MB (padded to Vpad rows)

  // weight prep (2 launches)
  {
    int n8hp = Hd * Hd / 8;
    int n8cast = Vd * Hd / 8, n8tot = Vpad * Hd / 8;
    int n8all = n8hp + n8tot;
    cast_weights<<<dim3((n8all + 255) / 256), dim3(256), 0, stream>>>(
        hp_w, hpwB, n8hp, eow, eowB, n8cast, n8tot);
  }
  transpose_cast2<<<dim3((Fd / 32) * (Hd / 32), 1, 2 * Ld), dim3(32, 8), 0, stream>>>(
      W1, W1t, W2, W2t);

  // embedding gather + LN_0
  ln_gather<<<dim3(Md / 4), dim3(256), 0, stream>>>(ids, emb, ln_w, ln_b, h, ybf);

  auto gemm1 = [&](int l) {
    gemm_bt256<0><<<dim3(Fd / 128, Md / 256), dim3(512), 0, stream>>>(
        ybf, W1t + (size_t)l * Fd * Hd, b1 + (size_t)l * Fd, (float*)nullptr, abf,
        Md, Fd, Hd, Hd);
  };

  // ---- stack 1 ----
  for (int l = 0; l < Ld; l++) {
    gemm1(l);
    if (l < Ld - 1)
      gemm2_ln<0><<<dim3(Md / 64), dim3(256), 0, stream>>>(
          abf, W2t + (size_t)l * Hd * Fd, b2 + (size_t)l * Hd,
          ln_w + (size_t)(l + 1) * Hd, ln_b + (size_t)(l + 1) * Hd, h, ybf,
          (float*)nullptr, Fd);
    else  // L5: residual + cast-only (feeds hp)
      gemm2_ln<1><<<dim3(Md / 64), dim3(256), 0, stream>>>(
          abf, W2t + (size_t)l * Hd * Fd, b2 + (size_t)l * Hd,
          (const float*)nullptr, (const float*)nullptr, h, ybf, (float*)nullptr, Fd);
  }

  // ---- hp projection: h = ybf @ hpw^T + hp_b; ybf = LN_0(h) ----
  gemm2_ln<2><<<dim3(Md / 64), dim3(256), 0, stream>>>(
      ybf, hpwB, hp_b, ln_w, ln_b, h, ybf, (float*)nullptr, Hd);

  // ---- stack 2 ----
  for (int l = 0; l < Ld; l++) {
    gemm1(l);
    if (l < Ld - 1)
      gemm2_ln<0><<<dim3(Md / 64), dim3(256), 0, stream>>>(
          abf, W2t + (size_t)l * Hd * Fd, b2 + (size_t)l * Hd,
          ln_w + (size_t)(l + 1) * Hd, ln_b + (size_t)(l + 1) * Hd, h, ybf,
          (float*)nullptr, Fd);
    else  // final: residual + LN_f + tail write, no h store
      gemm2_ln<3><<<dim3(Md / 64), dim3(256), 0, stream>>>(
          abf, W2t + (size_t)l * Hd * Fd, b2 + (size_t)l * Hd, lnf_w, lnf_b, h, ybf,
          out + (size_t)Md * Vd, Fd);
  }

  // ---- logits ----
  gemm_logits<<<dim3((Vpad / 256) * (Md / 256)), dim3(512), 0, stream>>>(
      ybf, eowB, out, Md, Vd, Hd, Hd);
}

// Round 13
// 930.128 us; speedup vs baseline: 1.4245x; 1.4245x over previous
//
#include <hip/hip_runtime.h>
#include <hip/hip_bf16.h>
#include <cstdint>

using bf16 = __hip_bfloat16;
typedef __bf16 bf16x8 __attribute__((ext_vector_type(8)));
typedef float f32x4 __attribute__((ext_vector_type(4)));

constexpr int Hd = 512;
constexpr int Ld = 6;
constexpr int Fd = 2048;
constexpr int Vd = 50304;
constexpr int Vpad = 50432;  // 197*256
constexpr int Md = 4096;     // B*S = 4*1024

// ---------- helpers ----------
__device__ __forceinline__ unsigned short f2b(float x) {
  return __builtin_bit_cast(unsigned short, __float2bfloat16(x));
}

__device__ __forceinline__ float gelu_tanh(float x) {
  const float c = 0.7978845608028654f;  // sqrt(2/pi)
  float x3 = x * x * x;
  return 0.5f * x * (1.0f + tanhf(c * (x + 0.044715f * x3)));
}

__device__ __forceinline__ void load16_lds(const bf16* g, bf16* l) {
  __builtin_amdgcn_global_load_lds(
      (const __attribute__((address_space(1))) void*)g,
      (__attribute__((address_space(3))) void*)l, 16, 0, 0);
}

// ---------- combined weight cast: hp (n8hp) then eow+pad (n8cast/n8tot) ----------
__global__ __launch_bounds__(256) void cast_weights(
    const float* __restrict__ hp, bf16* __restrict__ hpB, int n8hp,
    const float* __restrict__ eow, bf16* __restrict__ eowB, int n8cast, int n8tot) {
  int i = blockIdx.x * 256 + threadIdx.x;
  if (i < n8hp) {
    const float4* p = (const float4*)hp;
    float4 a = p[2 * i], b = p[2 * i + 1];
    uint4 o = {(unsigned)f2b(a.x) | ((unsigned)f2b(a.y) << 16),
               (unsigned)f2b(a.z) | ((unsigned)f2b(a.w) << 16),
               (unsigned)f2b(b.x) | ((unsigned)f2b(b.y) << 16),
               (unsigned)f2b(b.z) | ((unsigned)f2b(b.w) << 16)};
    ((uint4*)hpB)[i] = o;
    return;
  }
  int j = i - n8hp;
  if (j >= n8tot) return;
  if (j < n8cast) {
    const float4* p = (const float4*)eow;
    float4 a = p[2 * j], b = p[2 * j + 1];
    uint4 o = {(unsigned)f2b(a.x) | ((unsigned)f2b(a.y) << 16),
               (unsigned)f2b(a.z) | ((unsigned)f2b(a.w) << 16),
               (unsigned)f2b(b.x) | ((unsigned)f2b(b.y) << 16),
               (unsigned)f2b(b.z) | ((unsigned)f2b(b.w) << 16)};
    ((uint4*)eowB)[j] = o;
  } else {
    ((uint4*)eowB)[j] = uint4{0, 0, 0, 0};
  }
}

// ---------- combined transpose+cast for W1 (z<6: R=Hd,C=Fd) and W2 (z>=6: R=Fd,C=Hd) ----------
__global__ void transpose_cast2(const float* __restrict__ W1, bf16* __restrict__ W1t,
                                const float* __restrict__ W2, bf16* __restrict__ W2t) {
  __shared__ float tile[32][33];
  const int z = blockIdx.z;
  const bool isW1 = z < Ld;
  const int layer = isW1 ? z : z - Ld;
  const int R = isW1 ? Hd : Fd;
  const int C = isW1 ? Fd : Hd;
  const float* in = (isW1 ? W1 : W2) + (size_t)layer * R * C;
  bf16* out = (isW1 ? W1t : W2t) + (size_t)layer * R * C;
  const int tilesX = C >> 5;
  const int bx = blockIdx.x % tilesX;
  const int by = blockIdx.x / tilesX;
  int c0 = bx * 32, r0 = by * 32;
#pragma unroll
  for (int i = 0; i < 4; i++) {
    int r = r0 + threadIdx.y + i * 8;
    tile[threadIdx.y + i * 8][threadIdx.x] = in[(size_t)r * C + c0 + threadIdx.x];
  }
  __syncthreads();
#pragma unroll
  for (int i = 0; i < 4; i++) {
    int c = c0 + threadIdx.y + i * 8;
    out[(size_t)c * R + r0 + threadIdx.x] = (bf16)tile[threadIdx.x][threadIdx.y + i * 8];
  }
}

// ---------- layernorm, one wave per row, with fused split-K reduce / gather / tail ----------
// MODE 1: x = h + fb[col] + p0 + p1; h = x    (finish gemm2 split-K + residual)
// MODE 2: x = p0 + p1 + fb[col];     h = x    (finish hp split-K, overwrite)
// MODE 3: x = emb[ids[row]];         h = x    (fused embedding gather + LN)
// MODE 4: MODE 1 + tail: rows with (row&1023)==1023 also write x to out2[b*Hd..]
template <int MODE>
__global__ __launch_bounds__(256) void ln_rows(
    const float* __restrict__ h, const float* __restrict__ p0,
    const float* __restrict__ p1, const float* __restrict__ fb,
    const float* __restrict__ w, const float* __restrict__ b,
    float* __restrict__ hout, bf16* __restrict__ y,
    const int* __restrict__ ids, const float* __restrict__ emb,
    float* __restrict__ out2) {
  int row = blockIdx.x * 4 + (threadIdx.x >> 6);
  int lane = threadIdx.x & 63;
  size_t base = (size_t)row * Hd + lane * 8;
  float xv[8];
  if constexpr (MODE == 3) {
    int id = ids[row];
    const float* src = emb + (size_t)id * Hd + lane * 8;
    *(float4*)&xv[0] = *(const float4*)(src);
    *(float4*)&xv[4] = *(const float4*)(src + 4);
    *(float4*)(hout + base) = make_float4(xv[0], xv[1], xv[2], xv[3]);
    *(float4*)(hout + base + 4) = make_float4(xv[4], xv[5], xv[6], xv[7]);
  } else {
    float4 q0 = *(const float4*)(p0 + base), q1 = *(const float4*)(p0 + base + 4);
    float4 r0 = *(const float4*)(p1 + base), r1 = *(const float4*)(p1 + base + 4);
    float4 f0 = *(const float4*)(fb + lane * 8), f1 = *(const float4*)(fb + lane * 8 + 4);
    xv[0] = q0.x + r0.x + f0.x; xv[1] = q0.y + r0.y + f0.y;
    xv[2] = q0.z + r0.z + f0.z; xv[3] = q0.w + r0.w + f0.w;
    xv[4] = q1.x + r1.x + f1.x; xv[5] = q1.y + r1.y + f1.y;
    xv[6] = q1.z + r1.z + f1.z; xv[7] = q1.w + r1.w + f1.w;
    if constexpr (MODE == 1 || MODE == 4) {
      float4 a0 = *(const float4*)(h + base), a1 = *(const float4*)(h + base + 4);
      xv[0] += a0.x; xv[1] += a0.y; xv[2] += a0.z; xv[3] += a0.w;
      xv[4] += a1.x; xv[5] += a1.y; xv[6] += a1.z; xv[7] += a1.w;
    }
    *(float4*)(hout + base) = make_float4(xv[0], xv[1], xv[2], xv[3]);
    *(float4*)(hout + base + 4) = make_float4(xv[4], xv[5], xv[6], xv[7]);
    if constexpr (MODE == 4) {
      if ((row & 1023) == 1023) {
        int bb = row >> 10;
        float* dst = out2 + (size_t)bb * Hd + lane * 8;
        *(float4*)(dst) = make_float4(xv[0], xv[1], xv[2], xv[3]);
        *(float4*)(dst + 4) = make_float4(xv[4], xv[5], xv[6], xv[7]);
      }
    }
  }
  float s = 0.f;
#pragma unroll
  for (int j = 0; j < 8; j++) s += xv[j];
#pragma unroll
  for (int off = 1; off < 64; off <<= 1) s += __shfl_xor(s, off);
  float mu = s * (1.0f / 512.0f);
  float s2 = 0.f;
#pragma unroll
  for (int j = 0; j < 8; j++) {
    xv[j] -= mu;
    s2 += xv[j] * xv[j];
  }
#pragma unroll
  for (int off = 1; off < 64; off <<= 1) s2 += __shfl_xor(s2, off);
  float scale = rsqrtf(s2 * (1.0f / 512.0f) + 1e-5f);
  float o[8];
#pragma unroll
  for (int j = 0; j < 8; j++) {
    float wj = w[lane * 8 + j], bj = b[lane * 8 + j];
    o[j] = xv[j] * scale * wj + bj;
  }
  uint4 pk = {(unsigned)f2b(o[0]) | ((unsigned)f2b(o[1]) << 16),
              (unsigned)f2b(o[2]) | ((unsigned)f2b(o[3]) << 16),
              (unsigned)f2b(o[4]) | ((unsigned)f2b(o[5]) << 16),
              (unsigned)f2b(o[6]) | ((unsigned)f2b(o[7]) << 16)};
  *(uint4*)(y + base) = pk;
}

// ---------- finish split-K gemm2 of stack1: h += fb + p0 + p1, also emit bf16 ----------
__global__ __launch_bounds__(256) void finish2(
    const float* __restrict__ p0, const float* __restrict__ p1,
    const float* __restrict__ fb, float* __restrict__ h, bf16* __restrict__ hbf) {
  int i = blockIdx.x * 256 + threadIdx.x;  // 8 elems each; grid covers 2M elems
  size_t base = (size_t)i * 8;
  int col = (int)(base & 511);
  float x[8];
#pragma unroll
  for (int j = 0; j < 8; j += 4) {
    float4 a = *(const float4*)(h + base + j);
    float4 q = *(const float4*)(p0 + base + j);
    float4 r = *(const float4*)(p1 + base + j);
    float4 f = *(const float4*)(fb + col + j);
    x[j] = a.x + q.x + r.x + f.x; x[j + 1] = a.y + q.y + r.y + f.y;
    x[j + 2] = a.z + q.z + r.z + f.z; x[j + 3] = a.w + q.w + r.w + f.w;
    *(float4*)(h + base + j) = make_float4(x[j], x[j + 1], x[j + 2], x[j + 3]);
  }
  uint4 pk = {(unsigned)f2b(x[0]) | ((unsigned)f2b(x[1]) << 16),
              (unsigned)f2b(x[2]) | ((unsigned)f2b(x[3]) << 16),
              (unsigned)f2b(x[4]) | ((unsigned)f2b(x[5]) << 16),
              (unsigned)f2b(x[6]) | ((unsigned)f2b(x[7]) << 16)};
  *(uint4*)(hbf + base) = pk;
}

// ============ GEMM kernels: BK=64, conflict-free XOR swizzle ============
// LDS layout per operand tile: rows of 64 bf16 (128B) = 8 chunks of 16B.
// Swizzle (both sides): LDS[row][d] holds global[row][d ^ (row&7)].

// ---------- GEMM 128x128 tile, BK=64, 256 thr, 3-slot counted-vmcnt ----------
// EPI 0: out_bf16 = gelu(acc + bias)
// EPI 4: out_f32[z*M*N + idx] = acc   (split-K partial)
template <int EPI>
__global__ __launch_bounds__(256) void gemm_bt(
    const bf16* __restrict__ A, const bf16* __restrict__ Bt,
    const float* __restrict__ bias, float* __restrict__ outF,
    bf16* __restrict__ outB, int M, int N, int Klen, int lda, int ldb) {
  constexpr int ASZ = 128 * 64;          // 8192 elems
  constexpr int TILE = 2 * ASZ;          // A + B = 32 KB
  __shared__ bf16 lds[3 * TILE];         // 96 KB
  const int tid = threadIdx.x;
  const int wave = tid >> 6;
  const int lane = tid & 63;
  const int wm = (wave >> 1) * 64;
  const int wn = (wave & 1) * 64;

  const int bn = blockIdx.x;
  const int bm = blockIdx.y;
  const int rowA0 = bm * 128;
  const int rowB0 = bn * 128;
  const int k0 = blockIdx.z * Klen;

  const bf16* srcA[4];
  const bf16* srcB[4];
#pragma unroll
  for (int r = 0; r < 4; r++) {
    int c = r * 256 + tid;
    int row = c >> 3, d = c & 7;
    int cw = d ^ (row & 7);
    srcA[r] = A + (size_t)(rowA0 + row) * lda + k0 + cw * 8;
    srcB[r] = Bt + (size_t)(rowB0 + row) * ldb + k0 + cw * 8;
  }

  f32x4 acc[4][4];
#pragma unroll
  for (int i = 0; i < 4; i++)
#pragma unroll
    for (int j = 0; j < 4; j++) acc[i][j] = (f32x4){0.f, 0.f, 0.f, 0.f};

  const int fr = lane & 15;
  const int hi = lane >> 4;
  const int swz = fr & 7;

  auto STAGE = [&](int slot) {
    bf16* dst = lds + slot * TILE;
#pragma unroll
    for (int r = 0; r < 4; r++) {
      load16_lds(srcA[r], dst + (r * 4 + wave) * 512);
      srcA[r] += 64;
      load16_lds(srcB[r], dst + ASZ + (r * 4 + wave) * 512);
      srcB[r] += 64;
    }
  };

  STAGE(0);
  STAGE(1);
  const int nIter = Klen >> 6;
  int cur = 0, stg = 2;
  for (int it = 0; it < nIter; ++it) {
    if (it < nIter - 1)
      asm volatile("s_waitcnt vmcnt(8)" ::: "memory");
    else
      asm volatile("s_waitcnt vmcnt(0)" ::: "memory");
    __builtin_amdgcn_s_barrier();
    __builtin_amdgcn_sched_barrier(0);
    if (it + 2 < nIter) STAGE(stg);
    const bf16* lA = lds + cur * TILE;
    const bf16* lB = lA + ASZ;
#pragma unroll
    for (int ks = 0; ks < 2; ks++) {
      bf16x8 af[4], bfr[4];
#pragma unroll
      for (int f = 0; f < 4; f++) {
        int rowa = wm + f * 16 + fr;
        af[f] = *(const bf16x8*)(lA + rowa * 64 + ((ks * 4 + hi) ^ swz) * 8);
        int rowb = wn + f * 16 + fr;
        bfr[f] = *(const bf16x8*)(lB + rowb * 64 + ((ks * 4 + hi) ^ swz) * 8);
      }
#pragma unroll
      for (int i = 0; i < 4; i++)
#pragma unroll
        for (int j = 0; j < 4; j++)
          acc[i][j] = __builtin_amdgcn_mfma_f32_16x16x32_bf16(af[i], bfr[j], acc[i][j], 0, 0, 0);
    }
    cur = (cur == 2) ? 0 : cur + 1;
    stg = (stg == 2) ? 0 : stg + 1;
  }

  if constexpr (EPI == 4) outF += (size_t)blockIdx.z * M * N;
  const int orow = hi * 4;
  const int ocol = fr;
#pragma unroll
  for (int i = 0; i < 4; i++) {
#pragma unroll
    for (int j = 0; j < 4; j++) {
      int row0 = rowA0 + wm + i * 16 + orow;
      int col = rowB0 + wn + j * 16 + ocol;
#pragma unroll
      for (int q = 0; q < 4; q++) {
        float v = acc[i][j][q];
        size_t idx = (size_t)(row0 + q) * N + col;
        if constexpr (EPI == 0) {
          outB[idx] = (bf16)gelu_tanh(v + bias[col]);
        } else {
          outF[idx] = v;
        }
      }
    }
  }
}

// ---------- GEMM 256x128 tile, BK=64, 512 thr, 3-slot counted-vmcnt (gemm1) ----------
template <int EPI>
__global__ __launch_bounds__(512) void gemm_bt256(
    const bf16* __restrict__ A, const bf16* __restrict__ Bt,
    const float* __restrict__ bias, float* __restrict__ outF,
    bf16* __restrict__ outB, int M, int N, int lda, int ldb) {
  constexpr int ASZ = 256 * 64;          // 32 KB
  constexpr int BSZ = 128 * 64;          // 16 KB
  constexpr int TILE = ASZ + BSZ;        // 48 KB
  __shared__ bf16 lds[3 * TILE];         // 144 KB
  const int tid = threadIdx.x;
  const int wave = tid >> 6;
  const int lane = tid & 63;
  const int wm = (wave >> 1) * 64;
  const int wn = (wave & 1) * 64;

  const int bn = blockIdx.x;
  const int bm = blockIdx.y;
  const int rowA0 = bm * 256;
  const int rowB0 = bn * 128;

  const bf16* srcA[4];
#pragma unroll
  for (int r = 0; r < 4; r++) {
    int c = r * 512 + tid;
    int row = c >> 3, d = c & 7;
    int cw = d ^ (row & 7);
    srcA[r] = A + (size_t)(rowA0 + row) * lda + cw * 8;
  }
  const bf16* srcB[2];
#pragma unroll
  for (int r = 0; r < 2; r++) {
    int c = r * 512 + tid;
    int row = c >> 3, d = c & 7;
    int cw = d ^ (row & 7);
    srcB[r] = Bt + (size_t)(rowB0 + row) * ldb + cw * 8;
  }

  f32x4 acc[4][4];
#pragma unroll
  for (int i = 0; i < 4; i++)
#pragma unroll
    for (int j = 0; j < 4; j++) acc[i][j] = (f32x4){0.f, 0.f, 0.f, 0.f};

  const int fr = lane & 15;
  const int hi = lane >> 4;
  const int swz = fr & 7;

  auto STAGE = [&](int slot) {
    bf16* dst = lds + slot * TILE;
#pragma unroll
    for (int r = 0; r < 4; r++) {
      load16_lds(srcA[r], dst + (r * 8 + wave) * 512);
      srcA[r] += 64;
    }
#pragma unroll
    for (int r = 0; r < 2; r++) {
      load16_lds(srcB[r], dst + ASZ + (r * 8 + wave) * 512);
      srcB[r] += 64;
    }
  };

  STAGE(0);
  STAGE(1);
  const int nIter = 512 >> 6;  // 8 iters
  int cur = 0, stg = 2;
  for (int it = 0; it < nIter; ++it) {
    if (it < nIter - 1)
      asm volatile("s_waitcnt vmcnt(6)" ::: "memory");
    else
      asm volatile("s_waitcnt vmcnt(0)" ::: "memory");
    __builtin_amdgcn_s_barrier();
    __builtin_amdgcn_sched_barrier(0);
    if (it + 2 < nIter) STAGE(stg);
    const bf16* lA = lds + cur * TILE;
    const bf16* lB = lA + ASZ;
#pragma unroll
    for (int ks = 0; ks < 2; ks++) {
      bf16x8 af[4], bfr[4];
#pragma unroll
      for (int f = 0; f < 4; f++) {
        int rowa = wm + f * 16 + fr;
        af[f] = *(const bf16x8*)(lA + rowa * 64 + ((ks * 4 + hi) ^ swz) * 8);
        int rowb = wn + f * 16 + fr;
        bfr[f] = *(const bf16x8*)(lB + rowb * 64 + ((ks * 4 + hi) ^ swz) * 8);
      }
#pragma unroll
      for (int i = 0; i < 4; i++)
#pragma unroll
        for (int j = 0; j < 4; j++)
          acc[i][j] = __builtin_amdgcn_mfma_f32_16x16x32_bf16(af[i], bfr[j], acc[i][j], 0, 0, 0);
    }
    cur = (cur == 2) ? 0 : cur + 1;
    stg = (stg == 2) ? 0 : stg + 1;
  }

  const int orow = hi * 4;
  const int ocol = fr;
#pragma unroll
  for (int i = 0; i < 4; i++) {
#pragma unroll
    for (int j = 0; j < 4; j++) {
      int row0 = rowA0 + wm + i * 16 + orow;
      int col = rowB0 + wn + j * 16 + ocol;
#pragma unroll
      for (int q = 0; q < 4; q++) {
        float v = acc[i][j][q];
        size_t idx = (size_t)(row0 + q) * N + col;
        if constexpr (EPI == 0) {
          outB[idx] = (bf16)gelu_tanh(v + bias[col]);
        } else {
          outF[idx] = v;
        }
      }
    }
  }
}

// ---------- logits GEMM: 256x256 tile, BK=64, 512 thr, 2-slot 2-barrier ----------
__global__ __launch_bounds__(512, 1) void gemm_logits(
    const bf16* __restrict__ A, const bf16* __restrict__ Bt,
    float* __restrict__ outF, int M, int N, int lda, int ldb) {
  constexpr int ASZ = 256 * 64;     // 32 KB
  constexpr int TILE = 2 * ASZ;     // 64 KB
  __shared__ bf16 lds[2 * TILE];    // 128 KB
  const int tid = threadIdx.x;
  const int wave = tid >> 6;
  const int lane = tid & 63;
  const int wm = (wave >> 2) * 128;  // 0,128
  const int wn = (wave & 3) * 64;    // 0,64,128,192

  const int per = gridDim.x >> 3;
  const int wg = (blockIdx.x & 7) * per + (blockIdx.x >> 3);
  const int bm = wg & 15;
  const int bn = wg >> 4;
  const int rowA0 = bm * 256;
  const int rowB0 = bn * 256;

  const bf16* srcA[4];
  const bf16* srcB[4];
#pragma unroll
  for (int r = 0; r < 4; r++) {
    int c = r * 512 + tid;
    int row = c >> 3, d = c & 7;
    int cw = d ^ (row & 7);
    srcA[r] = A + (size_t)(rowA0 + row) * lda + cw * 8;
    srcB[r] = Bt + (size_t)(rowB0 + row) * ldb + cw * 8;
  }

  f32x4 acc[8][4];
#pragma unroll
  for (int i = 0; i < 8; i++)
#pragma unroll
    for (int j = 0; j < 4; j++) acc[i][j] = (f32x4){0.f, 0.f, 0.f, 0.f};

  const int fr = lane & 15;
  const int hi = lane >> 4;
  const int swz = fr & 7;

  auto STAGE = [&](int slot) {
    bf16* dst = lds + slot * TILE;
#pragma unroll
    for (int r = 0; r < 4; r++) {
      load16_lds(srcA[r], dst + (r * 8 + wave) * 512);
      srcA[r] += 64;
      load16_lds(srcB[r], dst + ASZ + (r * 8 + wave) * 512);
      srcB[r] += 64;
    }
  };

  STAGE(0);
  const int nIter = 512 >> 6;  // 8 iters
  for (int it = 0; it < nIter; ++it) {
    const int cur = it & 1;
    if (it + 1 < nIter) STAGE(cur ^ 1);
    if (it + 1 < nIter)
      asm volatile("s_waitcnt vmcnt(8)" ::: "memory");
    else
      asm volatile("s_waitcnt vmcnt(0)" ::: "memory");
    __builtin_amdgcn_s_barrier();
    __builtin_amdgcn_sched_barrier(0);
    const bf16* lA = lds + cur * TILE;
    const bf16* lB = lA + ASZ;
#pragma unroll
    for (int ks = 0; ks < 2; ks++) {
      bf16x8 af[8], bfr[4];
#pragma unroll
      for (int f = 0; f < 8; f++) {
        int rowa = wm + f * 16 + fr;
        af[f] = *(const bf16x8*)(lA + rowa * 64 + ((ks * 4 + hi) ^ swz) * 8);
      }
#pragma unroll
      for (int f = 0; f < 4; f++) {
        int rowb = wn + f * 16 + fr;
        bfr[f] = *(const bf16x8*)(lB + rowb * 64 + ((ks * 4 + hi) ^ swz) * 8);
      }
#pragma unroll
      for (int i = 0; i < 8; i++)
#pragma unroll
        for (int j = 0; j < 4; j++)
          acc[i][j] = __builtin_amdgcn_mfma_f32_16x16x32_bf16(af[i], bfr[j], acc[i][j], 0, 0, 0);
    }
    __builtin_amdgcn_s_barrier();
  }

  const int orow = hi * 4;
  const int ocol = fr;
#pragma unroll
  for (int i = 0; i < 8; i++) {
#pragma unroll
    for (int j = 0; j < 4; j++) {
      int row0 = rowA0 + wm + i * 16 + orow;
      int col = rowB0 + wn + j * 16 + ocol;
      if (col < N) {
#pragma unroll
        for (int q = 0; q < 4; q++)
          outF[(size_t)(row0 + q) * N + col] = acc[i][j][q];
      }
    }
  }
}

// ---------- launch ----------
extern "C" void kernel_launch(void* const* d_in, const int* in_sizes, int n_in,
                              void* d_out, int out_size, void* d_ws, size_t ws_size,
                              hipStream_t stream) {
  const int* ids = (const int*)d_in[0];
  const float* emb = (const float*)d_in[1];
  const float* hp_w = (const float*)d_in[2];
  const float* hp_b = (const float*)d_in[3];
  const float* ln_w = (const float*)d_in[4];
  const float* ln_b = (const float*)d_in[5];
  const float* W1 = (const float*)d_in[6];
  const float* b1 = (const float*)d_in[7];
  const float* W2 = (const float*)d_in[8];
  const float* b2 = (const float*)d_in[9];
  const float* lnf_w = (const float*)d_in[10];
  const float* lnf_b = (const float*)d_in[11];
  const float* eow = (const float*)d_in[12];
  float* out = (float*)d_out;

  char* ws = (char*)d_ws;
  float* h = (float*)(ws);                          // 8 MB
  bf16* ybf = (bf16*)(ws + (8u << 20));             // 4 MB
  bf16* abf = (bf16*)(ws + (12u << 20));            // 16 MB
  bf16* W1t = (bf16*)(ws + (28u << 20));            // 12 MB
  bf16* W2t = (bf16*)(ws + (40u << 20));            // 12 MB
  bf16* hpwB = (bf16*)(ws + (52u << 20));           // 0.5 MB
  bf16* eowB = (bf16*)(ws + (53u << 20));           // 51.6 MB (padded to Vpad rows)

  // split-K partials live in d_out's logits region (overwritten by logits GEMM later)
  float* p0 = out;                    // 2M floats
  float* p1 = out + (size_t)Md * Hd;  // next 2M floats

  // weight prep (2 launches total)
  {
    int n8hp = Hd * Hd / 8;
    int n8cast = Vd * Hd / 8, n8tot = Vpad * Hd / 8;
    int n8all = n8hp + n8tot;
    cast_weights<<<dim3((n8all + 255) / 256), dim3(256), 0, stream>>>(
        hp_w, hpwB, n8hp, eow, eowB, n8cast, n8tot);
  }
  transpose_cast2<<<dim3((Fd / 32) * (Hd / 32), 1, 2 * Ld), dim3(32, 8), 0, stream>>>(
      W1, W1t, W2, W2t);

  // one MLP layer: ln (with fused finish/gather) -> gemm1(256x128) -> split-K gemm2
  auto layer = [&](int l, int mode, const float* fb, const float* lw, const float* lb) {
    if (mode == 1)
      ln_rows<1><<<dim3(Md / 4), dim3(256), 0, stream>>>(h, p0, p1, fb, lw, lb, h, ybf,
                                                         nullptr, nullptr, nullptr);
    else if (mode == 2)
      ln_rows<2><<<dim3(Md / 4), dim3(256), 0, stream>>>(h, p0, p1, fb, lw, lb, h, ybf,
                                                         nullptr, nullptr, nullptr);
    else  // mode 3: gather+LN (first layer of stack 1)
      ln_rows<3><<<dim3(Md / 4), dim3(256), 0, stream>>>(h, p0, p1, fb, lw, lb, h, ybf,
                                                         ids, emb, nullptr);
    gemm_bt256<0><<<dim3(Fd / 128, Md / 256), dim3(512), 0, stream>>>(
        ybf, W1t + (size_t)l * Fd * Hd, b1 + (size_t)l * Fd, (float*)nullptr, abf,
        Md, Fd, Hd, Hd);
    gemm_bt<4><<<dim3(Hd / 128, Md / 128, 2), dim3(256), 0, stream>>>(
        abf, W2t + (size_t)l * Hd * Fd, (const float*)nullptr, p0, (bf16*)nullptr,
        Md, Hd, Fd / 2, Fd, Fd);
  };

  // ---- stack 1 ----
  layer(0, 3, nullptr, ln_w, ln_b);
  for (int l = 1; l < Ld; l++)
    layer(l, 1, b2 + (size_t)(l - 1) * Hd, ln_w + (size_t)l * Hd, ln_b + (size_t)l * Hd);
  finish2<<<dim3(Md * Hd / 8 / 256), dim3(256), 0, stream>>>(
      p0, p1, b2 + (size_t)(Ld - 1) * Hd, h, ybf);

  // ---- hp projection (split-K=2, finish fused into next LN) ----
  gemm_bt<4><<<dim3(Hd / 128, Md / 128, 2), dim3(256), 0, stream>>>(
      ybf, hpwB, (const float*)nullptr, p0, (bf16*)nullptr, Md, Hd, Hd / 2, Hd, Hd);

  // ---- stack 2 ----
  layer(0, 2, hp_b, ln_w, ln_b);
  for (int l = 1; l < Ld; l++)
    layer(l, 1, b2 + (size_t)(l - 1) * Hd, ln_w + (size_t)l * Hd, ln_b + (size_t)l * Hd);

  // ---- final LN (fused finish + tail write) + logits (256x256 BK=64, XCD swizzle) ----
  ln_rows<4><<<dim3(Md / 4), dim3(256), 0, stream>>>(
      h, p0, p1, b2 + (size_t)(Ld - 1) * Hd, lnf_w, lnf_b, h, ybf,
      nullptr, nullptr, out + (size_t)Md * Vd);
  gemm_logits<<<dim3((Vpad / 256) * (Md / 256)), dim3(512), 0, stream>>>(
      ybf, eowB, out, Md, Vd, Hd, Hd);
}